// Round 1
// baseline (5992.762 us; speedup 1.0000x reference)
//
#include <hip/hip_runtime.h>

// Problem constants (match reference setup_inputs()).
#define NN   100000   // nodes
#define RR   4        // relations
#define EE   500000   // edges per relation
#define FIN  256
#define FHID 128
#define FOUT 64

typedef unsigned short u16;
typedef __attribute__((ext_vector_type(8))) __bf16 bf16x8;
typedef __attribute__((ext_vector_type(4))) float  f32x4;

// float -> bf16 bits, round-to-nearest-even (finite inputs only).
__device__ __forceinline__ u16 f2bf(float f) {
    union { float f; unsigned int u; } v; v.f = f;
    unsigned int r = v.u + 0x7FFFu + ((v.u >> 16) & 1u);
    return (u16)(r >> 16);
}

__device__ __forceinline__ void atomAdd(float* p, float v) {
    unsafeAtomicAdd(p, v);   // guaranteed global_atomic_add_f32 on gfx950
}

// ---------------- small prep kernels ----------------

__global__ __launch_bounds__(256) void conv_bf16(const float* __restrict__ in,
                                                 u16* __restrict__ out, int n) {
    int i = blockIdx.x * 256 + threadIdx.x;
    if (i < n) out[i] = f2bf(in[i]);
}

// W [R][K][Nw] fp32 -> Wt [R][Nw][K] bf16 (transposed so B-fragments are contiguous)
__global__ __launch_bounds__(256) void conv_w_t(const float* __restrict__ W,
                                                u16* __restrict__ Wt,
                                                int K, int Nw, int total) {
    int i = blockIdx.x * 256 + threadIdx.x;
    if (i >= total) return;
    int r   = i / (K * Nw);
    int rem = i - r * K * Nw;
    int k   = rem / Nw;
    int n   = rem - k * Nw;
    Wt[((size_t)r * Nw + n) * K + k] = f2bf(W[i]);
}

__global__ __launch_bounds__(256) void deg_kernel(const int* __restrict__ src,
                                                  const int* __restrict__ dst,
                                                  float* __restrict__ dego,
                                                  float* __restrict__ degi) {
    int i = blockIdx.x * 256 + threadIdx.x;
    if (i >= RR * EE) return;
    int r = i / EE;
    atomAdd(&dego[r * NN + src[i]], 1.0f);
    atomAdd(&degi[r * NN + dst[i]], 1.0f);
}

__global__ __launch_bounds__(256) void rsqrt_kernel(float* __restrict__ d, int n) {
    int i = blockIdx.x * 256 + threadIdx.x;
    if (i < n) d[i] = rsqrtf(fmaxf(d[i], 1.0f));
}

__global__ __launch_bounds__(256) void coef_kernel(const int* __restrict__ src,
                                                   const int* __restrict__ dst,
                                                   const float* __restrict__ so,
                                                   const float* __restrict__ si,
                                                   float* __restrict__ coef) {
    int i = blockIdx.x * 256 + threadIdx.x;
    if (i >= RR * EE) return;
    int r = i / EE;
    coef[i] = so[r * NN + src[i]] * si[r * NN + dst[i]];
}

// sum of biases over relations (every node receives sum_r b_r)
__global__ void sumb_kernel(const float* __restrict__ b1, const float* __restrict__ b2,
                            float* __restrict__ s1, float* __restrict__ s2) {
    int j = threadIdx.x;
    if (j < FHID) {
        float v = 0.f;
        for (int r = 0; r < RR; ++r) v += b1[r * FHID + j];
        s1[j] = v;
    } else if (j < FHID + FOUT) {
        int j2 = j - FHID;
        float v = 0.f;
        for (int r = 0; r < RR; ++r) v += b2[r * FOUT + j2];
        s2[j2] = v;
    }
}

// ---------------- GEMM: Y[M][NW] = A[M][K](bf16) * Bt[NW][K](bf16)^T ----------------
// One 16x16 output tile per wave; mfma_f32_16x16x32_bf16, fp32 accumulate.
// Fragment maps (measured, learn_hip m89/m120): A[m=lane&15][k=quad*8+j],
// B[k=quad*8+j][n=lane&15], D: col=lane&15, row=quad*4+reg.
template<int NW, int K>
__global__ __launch_bounds__(256) void gemm_bt(const u16* __restrict__ A,
                                               const u16* __restrict__ Bt,
                                               float* __restrict__ Y) {
    constexpr int NT = NW / 16;
    int tid  = threadIdx.x;
    int gw   = blockIdx.x * 4 + (tid >> 6);
    int lane = tid & 63;
    int mt = gw / NT, nt = gw - mt * NT;
    int quad = lane >> 4, l15 = lane & 15;

    const bf16x8* Ap = (const bf16x8*)(A  + (size_t)(mt * 16 + l15) * K + quad * 8);
    const bf16x8* Bp = (const bf16x8*)(Bt + (size_t)(nt * 16 + l15) * K + quad * 8);

    f32x4 acc = {0.f, 0.f, 0.f, 0.f};
#pragma unroll
    for (int ks = 0; ks < K / 32; ++ks) {
        acc = __builtin_amdgcn_mfma_f32_16x16x32_bf16(Ap[ks * 4], Bp[ks * 4], acc, 0, 0, 0);
    }
    int row = mt * 16 + quad * 4;
    int col = nt * 16 + l15;
#pragma unroll
    for (int i = 0; i < 4; ++i)
        Y[(size_t)(row + i) * NW + col] = acc[i];
}

// ---------------- edge scatter: out[dst] += coef[e] * Y[src] ----------------
template<int F>
__global__ __launch_bounds__(256) void scatter_kernel(const float* __restrict__ Y,
                                                      const int* __restrict__ src,
                                                      const int* __restrict__ dst,
                                                      const float* __restrict__ coef,
                                                      float* __restrict__ out) {
    constexpr int TPE = F / 4;               // threads per edge (float4 each)
    int gid = blockIdx.x * 256 + threadIdx.x;
    int e = gid / TPE;
    int q = gid - e * TPE;
    if (e >= EE) return;
    float c = coef[e];
    int s = src[e], d = dst[e];
    float4 v = ((const float4*)Y)[(size_t)s * TPE + q];
    float* o = out + (size_t)d * F + q * 4;
    atomAdd(o + 0, v.x * c);
    atomAdd(o + 1, v.y * c);
    atomAdd(o + 2, v.z * c);
    atomAdd(o + 3, v.w * c);
}

// ---------------- epilogues ----------------

__global__ __launch_bounds__(256) void epi1(const float* __restrict__ agg,
                                            const float* __restrict__ sb,
                                            u16* __restrict__ H1, int n) {
    int i = blockIdx.x * 256 + threadIdx.x;
    if (i >= n) return;
    float v = agg[i] + sb[i & (FHID - 1)];
    H1[i] = f2bf(fmaxf(v, 0.f));
}

__global__ __launch_bounds__(256) void epi2(float* __restrict__ out,
                                            const float* __restrict__ sb, int n) {
    int i = blockIdx.x * 256 + threadIdx.x;
    if (i >= n) return;
    out[i] += sb[i & (FOUT - 1)];
}

// ---------------- launch ----------------

extern "C" void kernel_launch(void* const* d_in, const int* in_sizes, int n_in,
                              void* d_out, int out_size, void* d_ws, size_t ws_size,
                              hipStream_t stream) {
    const float* x    = (const float*)d_in[0];
    const int*   esrc = (const int*)  d_in[1];   // [R][E]
    const int*   edst = (const int*)  d_in[2];   // [R][E]
    const float* W1   = (const float*)d_in[3];   // [R][256][128]
    const float* b1   = (const float*)d_in[4];   // [R][128]
    const float* W2   = (const float*)d_in[5];   // [R][128][64]
    const float* b2   = (const float*)d_in[6];   // [R][64]
    float* out = (float*)d_out;                  // [N][64]

    char* w = (char*)d_ws;
    auto alloc = [&](size_t bytes) -> char* {
        char* p = w; w += (bytes + 255) & ~(size_t)255; return p;
    };
    // s_out and s_in must stay adjacent (rsqrt pass runs over both); R*N*4 is 256B-aligned.
    float* s_out = (float*)alloc((size_t)RR * NN * 4);
    float* s_in  = (float*)alloc((size_t)RR * NN * 4);
    float* coef  = (float*)alloc((size_t)RR * EE * 4);
    float* sb1   = (float*)alloc(FHID * 4);
    float* sb2   = (float*)alloc(FOUT * 4);
    u16*   Xbf   = (u16*)  alloc((size_t)NN * FIN * 2);
    u16*   W1t   = (u16*)  alloc((size_t)RR * FIN * FHID * 2);
    u16*   W2t   = (u16*)  alloc((size_t)RR * FHID * FOUT * 2);
    u16*   H1bf  = (u16*)  alloc((size_t)NN * FHID * 2);
    float* AGG1  = (float*)alloc((size_t)NN * FHID * 4);
    float* Yb    = (float*)alloc((size_t)NN * FHID * 4);
    // total ~190 MB of d_ws

    // zero the atomic accumulators (ws/out are poisoned 0xAA before every call)
    hipMemsetAsync(s_out, 0, (size_t)2 * RR * NN * 4, stream);
    hipMemsetAsync(AGG1, 0, (size_t)NN * FHID * 4, stream);
    hipMemsetAsync(out, 0, (size_t)NN * FOUT * 4, stream);

    // prep
    conv_bf16<<<(NN * FIN + 255) / 256, 256, 0, stream>>>(x, Xbf, NN * FIN);
    conv_w_t<<<(RR * FIN * FHID + 255) / 256, 256, 0, stream>>>(W1, W1t, FIN, FHID, RR * FIN * FHID);
    conv_w_t<<<(RR * FHID * FOUT + 255) / 256, 256, 0, stream>>>(W2, W2t, FHID, FOUT, RR * FHID * FOUT);
    deg_kernel<<<(RR * EE + 255) / 256, 256, 0, stream>>>(esrc, edst, s_out, s_in);
    rsqrt_kernel<<<(2 * RR * NN + 255) / 256, 256, 0, stream>>>(s_out, 2 * RR * NN);
    coef_kernel<<<(RR * EE + 255) / 256, 256, 0, stream>>>(esrc, edst, s_out, s_in, coef);
    sumb_kernel<<<1, 192, 0, stream>>>(b1, b2, sb1, sb2);

    // layer 1: per relation GEMM (N x 256 -> N x 128) then edge scatter into AGG1
    for (int r = 0; r < RR; ++r) {
        gemm_bt<FHID, FIN><<<(NN / 16) * (FHID / 16) / 4, 256, 0, stream>>>(
            Xbf, W1t + (size_t)r * FHID * FIN, Yb);
        scatter_kernel<FHID><<<EE * (FHID / 4) / 256, 256, 0, stream>>>(
            Yb, esrc + (size_t)r * EE, edst + (size_t)r * EE, coef + (size_t)r * EE, AGG1);
    }
    epi1<<<(NN * FHID + 255) / 256, 256, 0, stream>>>(AGG1, sb1, H1bf, NN * FHID);

    // layer 2: per relation GEMM (N x 128 -> N x 64) then scatter into d_out
    for (int r = 0; r < RR; ++r) {
        gemm_bt<FOUT, FHID><<<(NN / 16) * (FOUT / 16) / 4, 256, 0, stream>>>(
            H1bf, W2t + (size_t)r * FOUT * FHID, Yb);
        scatter_kernel<FOUT><<<EE * (FOUT / 4) / 256, 256, 0, stream>>>(
            Yb, esrc + (size_t)r * EE, edst + (size_t)r * EE, coef + (size_t)r * EE, out);
    }
    epi2<<<(NN * FOUT + 255) / 256, 256, 0, stream>>>(out, sb2, NN * FOUT);
}

// Round 2
// 1496.972 us; speedup vs baseline: 4.0033x; 4.0033x over previous
//
#include <hip/hip_runtime.h>

// Problem constants (match reference setup_inputs()).
#define NN   100000   // nodes
#define RR   4        // relations
#define EE   500000   // edges per relation
#define FIN  256
#define FHID 128
#define FOUT 64

typedef unsigned short u16;
typedef unsigned int   u32;
typedef __attribute__((ext_vector_type(8))) __bf16 bf16x8;
typedef __attribute__((ext_vector_type(4))) float  f32x4;

// float -> bf16 bits, round-to-nearest-even (finite inputs only).
__device__ __forceinline__ u16 f2bf(float f) {
    union { float f; u32 u; } v; v.f = f;
    u32 r = v.u + 0x7FFFu + ((v.u >> 16) & 1u);
    return (u16)(r >> 16);
}

// u32 holding two packed bf16 -> two floats (elem 2i in low half, 2i+1 high)
__device__ __forceinline__ float2 bfx2(u32 v) {
    union { u32 u; float f; } a, b;
    a.u = v << 16; b.u = v & 0xFFFF0000u;
    return {a.f, b.f};
}

__device__ __forceinline__ void atomAddF(float* p, float v) { unsafeAtomicAdd(p, v); }

// ---------------- prep kernels ----------------

__global__ __launch_bounds__(256) void conv_bf16(const float* __restrict__ in,
                                                 u16* __restrict__ out, int n) {
    int i = blockIdx.x * 256 + threadIdx.x;
    if (i < n) out[i] = f2bf(in[i]);
}

// W [R][K][Nw] fp32 -> Wt [R][Nw][K] bf16 (transposed: B-fragments contiguous)
__global__ __launch_bounds__(256) void conv_w_t(const float* __restrict__ W,
                                                u16* __restrict__ Wt,
                                                int K, int Nw, int total) {
    int i = blockIdx.x * 256 + threadIdx.x;
    if (i >= total) return;
    int r   = i / (K * Nw);
    int rem = i - r * K * Nw;
    int k   = rem / Nw;
    int n   = rem - k * Nw;
    Wt[((size_t)r * Nw + n) * K + k] = f2bf(W[i]);
}

__global__ __launch_bounds__(256) void deg_kernel(const int* __restrict__ src,
                                                  const int* __restrict__ dst,
                                                  float* __restrict__ dego,
                                                  float* __restrict__ degi) {
    int i = blockIdx.x * 256 + threadIdx.x;
    if (i >= RR * EE) return;
    int r = i / EE;
    atomAddF(&dego[r * NN + src[i]], 1.0f);
    atomAddF(&degi[r * NN + dst[i]], 1.0f);
}

// combined (over relations) in-degree counts; must run BEFORE rsqrt clamps s_in
__global__ __launch_bounds__(256) void counts_kernel(const float* __restrict__ s_in,
                                                     int* __restrict__ cnt) {
    int i = blockIdx.x * 256 + threadIdx.x;
    if (i < NN)
        cnt[i] = (int)(s_in[i] + s_in[NN + i] + s_in[2 * NN + i] + s_in[3 * NN + i]);
}

__global__ __launch_bounds__(256) void rsqrt_kernel(float* __restrict__ d, int n) {
    int i = blockIdx.x * 256 + threadIdx.x;
    if (i < n) d[i] = rsqrtf(fmaxf(d[i], 1.0f));
}

// single-block exclusive scan over cnt[NN] -> off[NN+1], cursor[NN]
__global__ __launch_bounds__(1024) void scan_kernel(const int* __restrict__ cnt,
                                                    int* __restrict__ off,
                                                    int* __restrict__ cursor) {
    __shared__ int tmp[1024];
    const int P = (NN + 1023) / 1024;   // 98 elements per thread
    int t = threadIdx.x;
    int lo = t * P, hi = min(NN, lo + P);
    int s = 0;
    for (int i = lo; i < hi; ++i) s += cnt[i];
    tmp[t] = s;
    __syncthreads();
    for (int d = 1; d < 1024; d <<= 1) {
        int v = (t >= d) ? tmp[t - d] : 0;
        __syncthreads();
        tmp[t] += v;
        __syncthreads();
    }
    int run = tmp[t] - s;   // exclusive prefix
    for (int i = lo; i < hi; ++i) { off[i] = run; cursor[i] = run; run += cnt[i]; }
    if (t == 1023) off[NN] = tmp[1023];
}

// bucket every edge by dst; meta = {r*NN+src, bits(coef)}
__global__ __launch_bounds__(256) void fill_kernel(const int* __restrict__ src,
                                                   const int* __restrict__ dst,
                                                   const float* __restrict__ so,
                                                   const float* __restrict__ si,
                                                   int* __restrict__ cursor,
                                                   int2* __restrict__ meta) {
    int i = blockIdx.x * 256 + threadIdx.x;
    if (i >= RR * EE) return;
    int r = i / EE;
    int s = src[i], d = dst[i];
    float c = so[r * NN + s] * si[r * NN + d];
    int pos = atomicAdd(&cursor[d], 1);
    meta[pos] = {r * NN + s, __float_as_int(c)};
}

// sum of biases over relations (every node receives sum_r b_r)
__global__ void sumb_kernel(const float* __restrict__ b1, const float* __restrict__ b2,
                            float* __restrict__ s1, float* __restrict__ s2) {
    int j = threadIdx.x;
    if (j < FHID) {
        float v = 0.f;
        for (int r = 0; r < RR; ++r) v += b1[r * FHID + j];
        s1[j] = v;
    } else if (j < FHID + FOUT) {
        int j2 = j - FHID;
        float v = 0.f;
        for (int r = 0; r < RR; ++r) v += b2[r * FOUT + j2];
        s2[j2] = v;
    }
}

// ---------------- GEMM: Y[M][NW](bf16) = A[M][K](bf16) * Bt[NW][K](bf16)^T ----------------
// One 16x16 tile per wave, mfma_f32_16x16x32_bf16, fp32 accumulate, bf16 store.
template<int NW, int K>
__global__ __launch_bounds__(256) void gemm_bt(const u16* __restrict__ A,
                                               const u16* __restrict__ Bt,
                                               u16* __restrict__ Y) {
    constexpr int NT = NW / 16;
    int tid  = threadIdx.x;
    int gw   = blockIdx.x * 4 + (tid >> 6);
    int lane = tid & 63;
    int mt = gw / NT, nt = gw - mt * NT;
    int quad = lane >> 4, l15 = lane & 15;

    const bf16x8* Ap = (const bf16x8*)(A  + (size_t)(mt * 16 + l15) * K + quad * 8);
    const bf16x8* Bp = (const bf16x8*)(Bt + (size_t)(nt * 16 + l15) * K + quad * 8);

    f32x4 acc = {0.f, 0.f, 0.f, 0.f};
#pragma unroll
    for (int ks = 0; ks < K / 32; ++ks)
        acc = __builtin_amdgcn_mfma_f32_16x16x32_bf16(Ap[ks * 4], Bp[ks * 4], acc, 0, 0, 0);

    int row = mt * 16 + quad * 4;
    int col = nt * 16 + l15;
#pragma unroll
    for (int i = 0; i < 4; ++i)
        Y[(size_t)(row + i) * NW + col] = f2bf(acc[i]);
}

// ---------------- gathers (CSR, one wave per dst node, no atomics) ----------------

// layer 1: F=128 -> 64 u32/row, 1 edge per wave-iteration; fused +bias, ReLU, bf16 pack
__global__ __launch_bounds__(256) void gather1(const u32* __restrict__ Y,     // [4*NN][64] packed bf16
                                               const int* __restrict__ off,
                                               const int2* __restrict__ meta,
                                               const float* __restrict__ sb,  // [128]
                                               u32* __restrict__ H1) {        // [NN][64] packed bf16
    int wid  = blockIdx.x * 4 + (threadIdx.x >> 6);
    int lane = threadIdx.x & 63;
    if (wid >= NN) return;
    int j = off[wid], end = off[wid + 1];
    float ax = 0.f, ay = 0.f;
    int2 m = (j < end) ? meta[j] : int2{0, 0};
    while (j < end) {
        int2 mn = (j + 1 < end) ? meta[j + 1] : m;   // prefetch next meta
        float c = __int_as_float(m.y);
        u32 v = Y[(size_t)m.x * 64 + lane];
        float2 f = bfx2(v);
        ax = fmaf(c, f.x, ax);
        ay = fmaf(c, f.y, ay);
        m = mn; ++j;
    }
    float2 b = ((const float2*)sb)[lane];
    ax = fmaxf(ax + b.x, 0.f);
    ay = fmaxf(ay + b.y, 0.f);
    H1[(size_t)wid * 64 + lane] = ((u32)f2bf(ay) << 16) | (u32)f2bf(ax);
}

// layer 2: F=64 -> 32 u32/row, 2 edges per wave-iteration; fused +bias, fp32 out
__global__ __launch_bounds__(256) void gather2(const u32* __restrict__ Y,     // [4*NN][32] packed bf16
                                               const int* __restrict__ off,
                                               const int2* __restrict__ meta,
                                               const float* __restrict__ sb,  // [64]
                                               float* __restrict__ out) {     // [NN][64] fp32
    int wid  = blockIdx.x * 4 + (threadIdx.x >> 6);
    int lane = threadIdx.x & 63;
    if (wid >= NN) return;
    int sub = lane >> 5, col = lane & 31;
    int end = off[wid + 1];
    int j = off[wid] + sub;
    float ax = 0.f, ay = 0.f;
    int2 m = (j < end) ? meta[j] : int2{0, 0};
    while (j < end) {
        int2 mn = (j + 2 < end) ? meta[j + 2] : m;
        float c = __int_as_float(m.y);
        u32 v = Y[(size_t)m.x * 32 + col];
        float2 f = bfx2(v);
        ax = fmaf(c, f.x, ax);
        ay = fmaf(c, f.y, ay);
        m = mn; j += 2;
    }
    ax += __shfl_xor(ax, 32);
    ay += __shfl_xor(ay, 32);
    if (sub == 0) {
        float2 b = ((const float2*)sb)[col];
        float2 o = {ax + b.x, ay + b.y};
        ((float2*)out)[(size_t)wid * 32 + col] = o;
    }
}

// ---------------- launch ----------------

extern "C" void kernel_launch(void* const* d_in, const int* in_sizes, int n_in,
                              void* d_out, int out_size, void* d_ws, size_t ws_size,
                              hipStream_t stream) {
    const float* x    = (const float*)d_in[0];
    const int*   esrc = (const int*)  d_in[1];   // [R][E]
    const int*   edst = (const int*)  d_in[2];   // [R][E]
    const float* W1   = (const float*)d_in[3];   // [R][256][128]
    const float* b1   = (const float*)d_in[4];   // [R][128]
    const float* W2   = (const float*)d_in[5];   // [R][128][64]
    const float* b2   = (const float*)d_in[6];   // [R][64]
    float* out = (float*)d_out;                  // [N][64]

    char* w = (char*)d_ws;
    auto alloc = [&](size_t bytes) -> char* {
        char* p = w; w += (bytes + 255) & ~(size_t)255; return p;
    };
    // s_out/s_in adjacent (one rsqrt pass covers both)
    float* s_out  = (float*)alloc((size_t)RR * NN * 4);          // 1.6 MB
    float* s_in   = (float*)alloc((size_t)RR * NN * 4);          // 1.6 MB
    int*   cnt    = (int*)  alloc((size_t)NN * 4);
    int*   off    = (int*)  alloc((size_t)(NN + 1) * 4);
    int*   cursor = (int*)  alloc((size_t)NN * 4);
    float* sb1    = (float*)alloc(FHID * 4);
    float* sb2    = (float*)alloc(FOUT * 4);
    u16*   W1t    = (u16*)  alloc((size_t)RR * FIN * FHID * 2);
    u16*   W2t    = (u16*)  alloc((size_t)RR * FHID * FOUT * 2);
    int2*  meta   = (int2*) alloc((size_t)RR * EE * 8);          // 16 MB
    u16*   Xbf    = (u16*)  alloc((size_t)NN * FIN * 2);         // 51.2 MB
    u16*   Yall   = (u16*)  alloc((size_t)RR * NN * FHID * 2);   // 102.4 MB
    // H1 aliases Xbf: Xbf is dead once layer-1 GEMMs have run; H1 (25.6 MB) fits.
    u16*   H1bf   = Xbf;
    // total ~175 MB of d_ws

    hipMemsetAsync(s_out, 0, (size_t)2 * RR * NN * 4, stream);   // covers s_in too

    // prep
    conv_bf16<<<(NN * FIN + 255) / 256, 256, 0, stream>>>(x, Xbf, NN * FIN);
    conv_w_t<<<(RR * FIN * FHID + 255) / 256, 256, 0, stream>>>(W1, W1t, FIN, FHID, RR * FIN * FHID);
    conv_w_t<<<(RR * FHID * FOUT + 255) / 256, 256, 0, stream>>>(W2, W2t, FHID, FOUT, RR * FHID * FOUT);
    deg_kernel<<<(RR * EE + 255) / 256, 256, 0, stream>>>(esrc, edst, s_out, s_in);
    counts_kernel<<<(NN + 255) / 256, 256, 0, stream>>>(s_in, cnt);
    rsqrt_kernel<<<(2 * RR * NN + 255) / 256, 256, 0, stream>>>(s_out, 2 * RR * NN);
    scan_kernel<<<1, 1024, 0, stream>>>(cnt, off, cursor);
    fill_kernel<<<(RR * EE + 255) / 256, 256, 0, stream>>>(esrc, edst, s_out, s_in, cursor, meta);
    sumb_kernel<<<1, 192, 0, stream>>>(b1, b2, sb1, sb2);

    // layer 1: per-relation GEMM into Yall[r], then one combined gather (fused bias+ReLU+bf16)
    for (int r = 0; r < RR; ++r)
        gemm_bt<FHID, FIN><<<(NN / 16) * (FHID / 16) / 4, 256, 0, stream>>>(
            Xbf, W1t + (size_t)r * FHID * FIN, Yall + (size_t)r * NN * FHID);
    gather1<<<(NN + 3) / 4, 256, 0, stream>>>((const u32*)Yall, off, meta, sb1, (u32*)H1bf);

    // layer 2: per-relation GEMM into Yall[r] (reused, now [r][N][64]), combined gather (fused bias)
    for (int r = 0; r < RR; ++r)
        gemm_bt<FOUT, FHID><<<(NN / 16) * (FOUT / 16) / 4, 256, 0, stream>>>(
            H1bf, W2t + (size_t)r * FOUT * FHID, Yall + (size_t)r * NN * FOUT);
    gather2<<<(NN + 3) / 4, 256, 0, stream>>>((const u32*)Yall, off, meta, sb2, out);
}

// Round 3
// 1069.762 us; speedup vs baseline: 5.6020x; 1.3994x over previous
//
#include <hip/hip_runtime.h>

// Problem constants (match reference setup_inputs()).
#define NN   100000   // nodes
#define RR   4        // relations
#define EE   500000   // edges per relation
#define FIN  256
#define FHID 128
#define FOUT 64
#define NBLK ((NN + 255) / 256)   // 391 scan blocks

typedef unsigned short u16;
typedef unsigned int   u32;
typedef __attribute__((ext_vector_type(8))) __bf16 bf16x8;
typedef __attribute__((ext_vector_type(4))) float  f32x4;

// float -> bf16 bits, round-to-nearest-even (finite inputs only).
__device__ __forceinline__ u16 f2bf(float f) {
    union { float f; u32 u; } v; v.f = f;
    u32 r = v.u + 0x7FFFu + ((v.u >> 16) & 1u);
    return (u16)(r >> 16);
}

// u32 holding two packed bf16 -> two floats (elem 2i low half, 2i+1 high)
__device__ __forceinline__ float2 bfx2(u32 v) {
    union { u32 u; float f; } a, b;
    a.u = v << 16; b.u = v & 0xFFFF0000u;
    return {a.f, b.f};
}

__device__ __forceinline__ void atomAddF(float* p, float v) { unsafeAtomicAdd(p, v); }

// ---------------- prep kernels ----------------

// fp32 -> packed bf16 pairs (u32), 2 elements/thread
__global__ __launch_bounds__(256) void conv_bf16x2(const float2* __restrict__ in,
                                                   u32* __restrict__ out, int n2) {
    int i = blockIdx.x * 256 + threadIdx.x;
    if (i < n2) {
        float2 f = in[i];
        out[i] = ((u32)f2bf(f.y) << 16) | (u32)f2bf(f.x);
    }
}

// W [R][K][Nw] fp32 -> Wt [R*Nw][K] bf16 (transposed: B-fragments contiguous)
__global__ __launch_bounds__(256) void conv_w_t(const float* __restrict__ W,
                                                u16* __restrict__ Wt,
                                                int K, int Nw, int total) {
    int i = blockIdx.x * 256 + threadIdx.x;
    if (i >= total) return;
    int r   = i / (K * Nw);
    int rem = i - r * K * Nw;
    int k   = rem / Nw;
    int n   = rem - k * Nw;
    Wt[((size_t)r * Nw + n) * K + k] = f2bf(W[i]);
}

__global__ __launch_bounds__(256) void deg_kernel(const int* __restrict__ src,
                                                  const int* __restrict__ dst,
                                                  float* __restrict__ dego,
                                                  float* __restrict__ degi) {
    int i = blockIdx.x * 256 + threadIdx.x;
    if (i >= RR * EE) return;
    int r = i / EE;
    atomAddF(&dego[r * NN + src[i]], 1.0f);
    atomAddF(&degi[r * NN + dst[i]], 1.0f);
}

// combined (over relations) in-degree counts; BEFORE rsqrt clamps s_in
__global__ __launch_bounds__(256) void counts_kernel(const float* __restrict__ s_in,
                                                     int* __restrict__ cnt) {
    int i = blockIdx.x * 256 + threadIdx.x;
    if (i < NN)
        cnt[i] = (int)(s_in[i] + s_in[NN + i] + s_in[2 * NN + i] + s_in[3 * NN + i]);
}

__global__ __launch_bounds__(256) void rsqrt_kernel(float* __restrict__ d, int n) {
    int i = blockIdx.x * 256 + threadIdx.x;
    if (i < n) d[i] = rsqrtf(fmaxf(d[i], 1.0f));
}

// ---------------- grid-parallel exclusive scan (3 kernels) ----------------

__global__ __launch_bounds__(256) void blocksum_kernel(const int* __restrict__ cnt,
                                                       int* __restrict__ bsum) {
    __shared__ int sh[256];
    int i = blockIdx.x * 256 + threadIdx.x;
    int t = threadIdx.x;
    sh[t] = (i < NN) ? cnt[i] : 0;
    __syncthreads();
    for (int d = 128; d > 0; d >>= 1) {
        if (t < d) sh[t] += sh[t + d];
        __syncthreads();
    }
    if (t == 0) bsum[blockIdx.x] = sh[0];
}

__global__ __launch_bounds__(512) void scanb_kernel(const int* __restrict__ bsum,
                                                    int* __restrict__ boff) {
    __shared__ int sh[512];
    int t = threadIdx.x;
    int v = (t < NBLK) ? bsum[t] : 0;
    sh[t] = v;
    __syncthreads();
    for (int d = 1; d < 512; d <<= 1) {
        int u = (t >= d) ? sh[t - d] : 0;
        __syncthreads();
        sh[t] += u;
        __syncthreads();
    }
    if (t < NBLK) boff[t] = sh[t] - v;   // exclusive
}

__global__ __launch_bounds__(256) void offsets_kernel(const int* __restrict__ cnt,
                                                      const int* __restrict__ boff,
                                                      int* __restrict__ off,
                                                      int* __restrict__ cursor) {
    __shared__ int sh[256];
    int i = blockIdx.x * 256 + threadIdx.x;
    int t = threadIdx.x;
    int v = (i < NN) ? cnt[i] : 0;
    sh[t] = v;
    __syncthreads();
    for (int d = 1; d < 256; d <<= 1) {
        int u = (t >= d) ? sh[t - d] : 0;
        __syncthreads();
        sh[t] += u;
        __syncthreads();
    }
    int ex = boff[blockIdx.x] + sh[t] - v;   // exclusive prefix
    if (i < NN) { off[i] = ex; cursor[i] = ex; }
    if (i == NN - 1) off[NN] = ex + v;
}

// bucket every edge by dst; meta = {src*RR + r, bits(coef)}  (matches [N][R][F] Y layout)
__global__ __launch_bounds__(256) void fill_kernel(const int* __restrict__ src,
                                                   const int* __restrict__ dst,
                                                   const float* __restrict__ so,
                                                   const float* __restrict__ si,
                                                   int* __restrict__ cursor,
                                                   int2* __restrict__ meta) {
    int i = blockIdx.x * 256 + threadIdx.x;
    if (i >= RR * EE) return;
    int r = i / EE;
    int s = src[i], d = dst[i];
    float c = so[r * NN + s] * si[r * NN + d];
    int pos = atomicAdd(&cursor[d], 1);
    meta[pos] = {s * RR + r, __float_as_int(c)};
}

// sum of biases over relations (every node receives sum_r b_r)
__global__ void sumb_kernel(const float* __restrict__ b1, const float* __restrict__ b2,
                            float* __restrict__ s1, float* __restrict__ s2) {
    int j = threadIdx.x;
    if (j < FHID) {
        float v = 0.f;
        for (int r = 0; r < RR; ++r) v += b1[r * FHID + j];
        s1[j] = v;
    } else if (j < FHID + FOUT) {
        int j2 = j - FHID;
        float v = 0.f;
        for (int r = 0; r < RR; ++r) v += b2[r * FOUT + j2];
        s2[j2] = v;
    }
}

// ---------------- GEMM: Y[M][NW](bf16) = A[M][K](bf16) * Bt[NW][K](bf16)^T ----------------
// One 16x16 tile per wave, mfma_f32_16x16x32_bf16, fp32 accumulate, bf16 store.
// NW spans all relations (Bt rows = concat of relations' output cols).
template<int NW, int K>
__global__ __launch_bounds__(256) void gemm_bt(const u16* __restrict__ A,
                                               const u16* __restrict__ Bt,
                                               u16* __restrict__ Y) {
    constexpr int NT = NW / 16;
    int tid  = threadIdx.x;
    int gw   = blockIdx.x * 4 + (tid >> 6);
    int lane = tid & 63;
    int mt = gw / NT, nt = gw - mt * NT;
    int quad = lane >> 4, l15 = lane & 15;

    const bf16x8* Ap = (const bf16x8*)(A  + (size_t)(mt * 16 + l15) * K + quad * 8);
    const bf16x8* Bp = (const bf16x8*)(Bt + (size_t)(nt * 16 + l15) * K + quad * 8);

    f32x4 acc = {0.f, 0.f, 0.f, 0.f};
#pragma unroll
    for (int ks = 0; ks < K / 32; ++ks)
        acc = __builtin_amdgcn_mfma_f32_16x16x32_bf16(Ap[ks * 4], Bp[ks * 4], acc, 0, 0, 0);

    int row = mt * 16 + quad * 4;
    int col = nt * 16 + l15;
#pragma unroll
    for (int i = 0; i < 4; ++i)
        Y[(size_t)(row + i) * NW + col] = f2bf(acc[i]);
}

// ---------------- gathers (CSR, one wave per dst node, no atomics) ----------------
// Y layout: [N][R][F] packed bf16 -> row base (u32 units) = m.x * (F/2), m.x = src*4+r.

// layer 1: F=128 -> 64 u32/row; 4 edges in flight; fused +bias, ReLU, bf16 pack
__global__ __launch_bounds__(256) void gather1(const u32* __restrict__ Y,
                                               const int* __restrict__ off,
                                               const int2* __restrict__ meta,
                                               const float* __restrict__ sb,   // [128]
                                               u32* __restrict__ H1) {         // [NN][64] packed bf16
    int wid  = blockIdx.x * 4 + (threadIdx.x >> 6);
    int lane = threadIdx.x & 63;
    if (wid >= NN) return;
    int j = off[wid], end = off[wid + 1];
    float a0x = 0.f, a0y = 0.f, a1x = 0.f, a1y = 0.f;
    float a2x = 0.f, a2y = 0.f, a3x = 0.f, a3y = 0.f;
    for (; j + 4 <= end; j += 4) {
        int2 m0 = meta[j], m1 = meta[j + 1], m2 = meta[j + 2], m3 = meta[j + 3];
        u32 v0 = Y[(size_t)m0.x * 64 + lane];
        u32 v1 = Y[(size_t)m1.x * 64 + lane];
        u32 v2 = Y[(size_t)m2.x * 64 + lane];
        u32 v3 = Y[(size_t)m3.x * 64 + lane];
        float2 f0 = bfx2(v0), f1 = bfx2(v1), f2 = bfx2(v2), f3 = bfx2(v3);
        float c0 = __int_as_float(m0.y), c1 = __int_as_float(m1.y);
        float c2 = __int_as_float(m2.y), c3 = __int_as_float(m3.y);
        a0x = fmaf(c0, f0.x, a0x); a0y = fmaf(c0, f0.y, a0y);
        a1x = fmaf(c1, f1.x, a1x); a1y = fmaf(c1, f1.y, a1y);
        a2x = fmaf(c2, f2.x, a2x); a2y = fmaf(c2, f2.y, a2y);
        a3x = fmaf(c3, f3.x, a3x); a3y = fmaf(c3, f3.y, a3y);
    }
    for (; j < end; ++j) {
        int2 m0 = meta[j];
        u32 v0 = Y[(size_t)m0.x * 64 + lane];
        float2 f0 = bfx2(v0);
        float c0 = __int_as_float(m0.y);
        a0x = fmaf(c0, f0.x, a0x); a0y = fmaf(c0, f0.y, a0y);
    }
    float2 b = ((const float2*)sb)[lane];
    float ax = fmaxf((a0x + a1x) + (a2x + a3x) + b.x, 0.f);
    float ay = fmaxf((a0y + a1y) + (a2y + a3y) + b.y, 0.f);
    H1[(size_t)wid * 64 + lane] = ((u32)f2bf(ay) << 16) | (u32)f2bf(ax);
}

// layer 2: F=64 -> 32 u32/row; 2 sub-waves x 2 chains = 4 edges in flight; fused +bias
__global__ __launch_bounds__(256) void gather2(const u32* __restrict__ Y,
                                               const int* __restrict__ off,
                                               const int2* __restrict__ meta,
                                               const float* __restrict__ sb,   // [64]
                                               float* __restrict__ out) {      // [NN][64] fp32
    int wid  = blockIdx.x * 4 + (threadIdx.x >> 6);
    int lane = threadIdx.x & 63;
    if (wid >= NN) return;
    int sub = lane >> 5, col = lane & 31;
    int end = off[wid + 1];
    int j = off[wid] + sub;
    float a0x = 0.f, a0y = 0.f, a1x = 0.f, a1y = 0.f;
    for (; j + 2 < end; j += 4) {     // this sub-wave: edges j and j+2
        int2 m0 = meta[j], m1 = meta[j + 2];
        u32 v0 = Y[(size_t)m0.x * 32 + col];
        u32 v1 = Y[(size_t)m1.x * 32 + col];
        float2 f0 = bfx2(v0), f1 = bfx2(v1);
        float c0 = __int_as_float(m0.y), c1 = __int_as_float(m1.y);
        a0x = fmaf(c0, f0.x, a0x); a0y = fmaf(c0, f0.y, a0y);
        a1x = fmaf(c1, f1.x, a1x); a1y = fmaf(c1, f1.y, a1y);
    }
    if (j < end) {
        int2 m0 = meta[j];
        u32 v0 = Y[(size_t)m0.x * 32 + col];
        float2 f0 = bfx2(v0);
        float c0 = __int_as_float(m0.y);
        a0x = fmaf(c0, f0.x, a0x); a0y = fmaf(c0, f0.y, a0y);
    }
    float ax = a0x + a1x, ay = a0y + a1y;
    ax += __shfl_xor(ax, 32);
    ay += __shfl_xor(ay, 32);
    if (sub == 0) {
        float2 b = ((const float2*)sb)[col];
        float2 o = {ax + b.x, ay + b.y};
        ((float2*)out)[(size_t)wid * 32 + col] = o;
    }
}

// ---------------- launch ----------------

extern "C" void kernel_launch(void* const* d_in, const int* in_sizes, int n_in,
                              void* d_out, int out_size, void* d_ws, size_t ws_size,
                              hipStream_t stream) {
    const float* x    = (const float*)d_in[0];
    const int*   esrc = (const int*)  d_in[1];   // [R][E]
    const int*   edst = (const int*)  d_in[2];   // [R][E]
    const float* W1   = (const float*)d_in[3];   // [R][256][128]
    const float* b1   = (const float*)d_in[4];   // [R][128]
    const float* W2   = (const float*)d_in[5];   // [R][128][64]
    const float* b2   = (const float*)d_in[6];   // [R][64]
    float* out = (float*)d_out;                  // [N][64]

    char* w = (char*)d_ws;
    auto alloc = [&](size_t bytes) -> char* {
        char* p = w; w += (bytes + 255) & ~(size_t)255; return p;
    };
    // s_out/s_in adjacent (one rsqrt pass covers both)
    float* s_out  = (float*)alloc((size_t)RR * NN * 4);          // 1.6 MB
    float* s_in   = (float*)alloc((size_t)RR * NN * 4);          // 1.6 MB
    int*   cnt    = (int*)  alloc((size_t)NN * 4);
    int*   off    = (int*)  alloc((size_t)(NN + 1) * 4);
    int*   cursor = (int*)  alloc((size_t)NN * 4);
    int*   bsum   = (int*)  alloc((size_t)NBLK * 4);
    int*   boff   = (int*)  alloc((size_t)NBLK * 4);
    float* sb1    = (float*)alloc(FHID * 4);
    float* sb2    = (float*)alloc(FOUT * 4);
    u16*   W1t    = (u16*)  alloc((size_t)RR * FIN * FHID * 2);
    u16*   W2t    = (u16*)  alloc((size_t)RR * FHID * FOUT * 2);
    int2*  meta   = (int2*) alloc((size_t)RR * EE * 8);          // 16 MB
    u16*   Xbf    = (u16*)  alloc((size_t)NN * FIN * 2);         // 51.2 MB
    u16*   Yall   = (u16*)  alloc((size_t)NN * RR * FHID * 2);   // 102.4 MB, [N][R][F]
    u16*   H1bf   = Xbf;    // Xbf dead after layer-1 GEMM; H1 (25.6 MB) fits
    // total ~175 MB of d_ws

    hipMemsetAsync(s_out, 0, (size_t)2 * RR * NN * 4, stream);   // covers s_in too

    // prep
    conv_bf16x2<<<(NN * FIN / 2 + 255) / 256, 256, 0, stream>>>((const float2*)x, (u32*)Xbf, NN * FIN / 2);
    conv_w_t<<<(RR * FIN * FHID + 255) / 256, 256, 0, stream>>>(W1, W1t, FIN, FHID, RR * FIN * FHID);
    conv_w_t<<<(RR * FHID * FOUT + 255) / 256, 256, 0, stream>>>(W2, W2t, FHID, FOUT, RR * FHID * FOUT);
    deg_kernel<<<(RR * EE + 255) / 256, 256, 0, stream>>>(esrc, edst, s_out, s_in);
    counts_kernel<<<NBLK, 256, 0, stream>>>(s_in, cnt);
    rsqrt_kernel<<<(2 * RR * NN + 255) / 256, 256, 0, stream>>>(s_out, 2 * RR * NN);
    blocksum_kernel<<<NBLK, 256, 0, stream>>>(cnt, bsum);
    scanb_kernel<<<1, 512, 0, stream>>>(bsum, boff);
    offsets_kernel<<<NBLK, 256, 0, stream>>>(cnt, boff, off, cursor);
    fill_kernel<<<(RR * EE + 255) / 256, 256, 0, stream>>>(esrc, edst, s_out, s_in, cursor, meta);
    sumb_kernel<<<1, 192, 0, stream>>>(b1, b2, sb1, sb2);

    // layer 1: ONE GEMM over all relations (NW = 4*128 = 512), then combined gather
    gemm_bt<RR * FHID, FIN><<<(NN / 16) * (RR * FHID / 16) / 4, 256, 0, stream>>>(Xbf, W1t, Yall);
    gather1<<<(NN + 3) / 4, 256, 0, stream>>>((const u32*)Yall, off, meta, sb1, (u32*)H1bf);

    // layer 2: ONE GEMM over all relations (NW = 4*64 = 256), then combined gather
    gemm_bt<RR * FOUT, FHID><<<(NN / 16) * (RR * FOUT / 16) / 4, 256, 0, stream>>>(H1bf, W2t, Yall);
    gather2<<<(NN + 3) / 4, 256, 0, stream>>>((const u32*)Yall, off, meta, sb2, out);
}

// Round 4
// 718.310 us; speedup vs baseline: 8.3429x; 1.4893x over previous
//
#include <hip/hip_runtime.h>

// Problem constants (match reference setup_inputs()).
#define NN   100000   // nodes
#define RR   4        // relations
#define EE   500000   // edges per relation
#define FIN  256
#define FHID 128
#define FOUT 64
#define NBLK ((NN + 255) / 256)   // 391 scan blocks

typedef unsigned short u16;
typedef unsigned int   u32;
typedef __attribute__((ext_vector_type(8))) __bf16 bf16x8;
typedef __attribute__((ext_vector_type(4))) float  f32x4;

// float -> bf16 bits, round-to-nearest-even (finite inputs only).
__device__ __forceinline__ u16 f2bf(float f) {
    union { float f; u32 u; } v; v.f = f;
    u32 r = v.u + 0x7FFFu + ((v.u >> 16) & 1u);
    return (u16)(r >> 16);
}

// u32 holding two packed bf16 -> two floats (elem 2i low half, 2i+1 high)
__device__ __forceinline__ float2 bfx2(u32 v) {
    union { u32 u; float f; } a, b;
    a.u = v << 16; b.u = v & 0xFFFF0000u;
    return {a.f, b.f};
}

__device__ __forceinline__ void atomAddF(float* p, float v) { unsafeAtomicAdd(p, v); }

// async global->LDS, 16 bytes per lane (global_load_lds_dwordx4)
typedef __attribute__((address_space(3))) u32 lds_u32;
typedef __attribute__((address_space(1))) const u32 gl_u32;
__device__ __forceinline__ void gload16(const void* g, void* l) {
    __builtin_amdgcn_global_load_lds((gl_u32*)g, (lds_u32*)l, 16, 0, 0);
}

// ---------------- prep kernels ----------------

// fp32 -> packed bf16 pairs (u32), 2 elements/thread
__global__ __launch_bounds__(256) void conv_bf16x2(const float2* __restrict__ in,
                                                   u32* __restrict__ out, int n2) {
    int i = blockIdx.x * 256 + threadIdx.x;
    if (i < n2) {
        float2 f = in[i];
        out[i] = ((u32)f2bf(f.y) << 16) | (u32)f2bf(f.x);
    }
}

// W [R][K][Nw] fp32 -> Wt [R*Nw][K] bf16 (transposed: B-fragments contiguous)
__global__ __launch_bounds__(256) void conv_w_t(const float* __restrict__ W,
                                                u16* __restrict__ Wt,
                                                int K, int Nw, int total) {
    int i = blockIdx.x * 256 + threadIdx.x;
    if (i >= total) return;
    int r   = i / (K * Nw);
    int rem = i - r * K * Nw;
    int k   = rem / Nw;
    int n   = rem - k * Nw;
    Wt[((size_t)r * Nw + n) * K + k] = f2bf(W[i]);
}

__global__ __launch_bounds__(256) void deg_kernel(const int* __restrict__ src,
                                                  const int* __restrict__ dst,
                                                  float* __restrict__ dego,
                                                  float* __restrict__ degi) {
    int i = blockIdx.x * 256 + threadIdx.x;
    if (i >= RR * EE) return;
    int r = i / EE;
    atomAddF(&dego[r * NN + src[i]], 1.0f);
    atomAddF(&degi[r * NN + dst[i]], 1.0f);
}

// combined (over relations) in-degree counts; BEFORE rsqrt clamps s_in
__global__ __launch_bounds__(256) void counts_kernel(const float* __restrict__ s_in,
                                                     int* __restrict__ cnt) {
    int i = blockIdx.x * 256 + threadIdx.x;
    if (i < NN)
        cnt[i] = (int)(s_in[i] + s_in[NN + i] + s_in[2 * NN + i] + s_in[3 * NN + i]);
}

__global__ __launch_bounds__(256) void rsqrt_kernel(float* __restrict__ d, int n) {
    int i = blockIdx.x * 256 + threadIdx.x;
    if (i < n) d[i] = rsqrtf(fmaxf(d[i], 1.0f));
}

// ---------------- grid-parallel exclusive scan (3 kernels) ----------------

__global__ __launch_bounds__(256) void blocksum_kernel(const int* __restrict__ cnt,
                                                       int* __restrict__ bsum) {
    __shared__ int sh[256];
    int i = blockIdx.x * 256 + threadIdx.x;
    int t = threadIdx.x;
    sh[t] = (i < NN) ? cnt[i] : 0;
    __syncthreads();
    for (int d = 128; d > 0; d >>= 1) {
        if (t < d) sh[t] += sh[t + d];
        __syncthreads();
    }
    if (t == 0) bsum[blockIdx.x] = sh[0];
}

__global__ __launch_bounds__(512) void scanb_kernel(const int* __restrict__ bsum,
                                                    int* __restrict__ boff) {
    __shared__ int sh[512];
    int t = threadIdx.x;
    int v = (t < NBLK) ? bsum[t] : 0;
    sh[t] = v;
    __syncthreads();
    for (int d = 1; d < 512; d <<= 1) {
        int u = (t >= d) ? sh[t - d] : 0;
        __syncthreads();
        sh[t] += u;
        __syncthreads();
    }
    if (t < NBLK) boff[t] = sh[t] - v;   // exclusive
}

__global__ __launch_bounds__(256) void offsets_kernel(const int* __restrict__ cnt,
                                                      const int* __restrict__ boff,
                                                      int* __restrict__ off,
                                                      int* __restrict__ cursor) {
    __shared__ int sh[256];
    int i = blockIdx.x * 256 + threadIdx.x;
    int t = threadIdx.x;
    int v = (i < NN) ? cnt[i] : 0;
    sh[t] = v;
    __syncthreads();
    for (int d = 1; d < 256; d <<= 1) {
        int u = (t >= d) ? sh[t - d] : 0;
        __syncthreads();
        sh[t] += u;
        __syncthreads();
    }
    int ex = boff[blockIdx.x] + sh[t] - v;   // exclusive prefix
    if (i < NN) { off[i] = ex; cursor[i] = ex; }
    if (i == NN - 1) off[NN] = ex + v;
}

// bucket every edge by dst; meta = {src*RR + r, bits(coef)}  (matches [N][R][F] Y layout)
__global__ __launch_bounds__(256) void fill_kernel(const int* __restrict__ src,
                                                   const int* __restrict__ dst,
                                                   const float* __restrict__ so,
                                                   const float* __restrict__ si,
                                                   int* __restrict__ cursor,
                                                   int2* __restrict__ meta) {
    int i = blockIdx.x * 256 + threadIdx.x;
    if (i >= RR * EE) return;
    int r = i / EE;
    int s = src[i], d = dst[i];
    float c = so[r * NN + s] * si[r * NN + d];
    int pos = atomicAdd(&cursor[d], 1);
    meta[pos] = {s * RR + r, __float_as_int(c)};
}

// sum of biases over relations (every node receives sum_r b_r)
__global__ void sumb_kernel(const float* __restrict__ b1, const float* __restrict__ b2,
                            float* __restrict__ s1, float* __restrict__ s2) {
    int j = threadIdx.x;
    if (j < FHID) {
        float v = 0.f;
        for (int r = 0; r < RR; ++r) v += b1[r * FHID + j];
        s1[j] = v;
    } else if (j < FHID + FOUT) {
        int j2 = j - FHID;
        float v = 0.f;
        for (int r = 0; r < RR; ++r) v += b2[r * FOUT + j2];
        s2[j2] = v;
    }
}

// ---------------- tiled GEMM (m97 structure) ----------------
// Y[M][NW](bf16) = A[M][K](bf16) @ Bt[NW][K](bf16)^T.
// 128x128 block tile, BK=32, 256 threads = 4 waves, each wave a 64x64 quadrant
// (4x4 grid of 16x16 mfma tiles). A+B staged via global_load_lds width=16.
// M rows clamped on staging (garbage rows unguarded in LDS but their outputs
// are store-guarded); NW, K must divide 128/32.
template<int NW, int K>
__global__ __launch_bounds__(256) void gemm_tile(const u16* __restrict__ A,
                                                 const u16* __restrict__ Bt,
                                                 u16* __restrict__ Y, int M) {
    __shared__ u16 As[128 * 32];
    __shared__ u16 Bs[128 * 32];
    int tid = threadIdx.x;
    int m0 = blockIdx.x * 128, n0 = blockIdx.y * 128;
    int wave = tid >> 6, lane = tid & 63;
    int quad = lane >> 4, l15 = lane & 15;
    int wm = (wave >> 1) * 64, wn = (wave & 1) * 64;

    // staging: thread t covers row t>>2 (and +64), 16B chunk (t&3)*8 elems
    int srow = tid >> 2;
    int scol = (tid & 3) * 8;
    const u16* Ag0 = A + (size_t)min(m0 + srow,      M - 1) * K + scol;
    const u16* Ag1 = A + (size_t)min(m0 + srow + 64, M - 1) * K + scol;
    const u16* Bg0 = Bt + (size_t)(n0 + srow) * K + scol;
    const u16* Bg1 = Bt + (size_t)(n0 + srow + 64) * K + scol;
    u16* As0 = As + tid * 8;            // == (srow*32 + scol) elems; lane-contiguous
    u16* As1 = As + 2048 + tid * 8;
    u16* Bs0 = Bs + tid * 8;
    u16* Bs1 = Bs + 2048 + tid * 8;

    // fragment read pointers (constant across K loop)
    const bf16x8* Ard = (const bf16x8*)(As + (wm + l15) * 32 + quad * 8);
    const bf16x8* Brd = (const bf16x8*)(Bs + (wn + l15) * 32 + quad * 8);

    f32x4 acc[4][4] = {};
    for (int k0 = 0; k0 < K; k0 += 32) {
        gload16(Ag0 + k0, As0);
        gload16(Ag1 + k0, As1);
        gload16(Bg0 + k0, Bs0);
        gload16(Bg1 + k0, Bs1);
        __syncthreads();
        bf16x8 af[4], bfr[4];
#pragma unroll
        for (int i = 0; i < 4; ++i) af[i]  = Ard[i * 64];   // +16 rows = 64 bf16x8
#pragma unroll
        for (int j = 0; j < 4; ++j) bfr[j] = Brd[j * 64];
#pragma unroll
        for (int i = 0; i < 4; ++i)
#pragma unroll
            for (int j = 0; j < 4; ++j)
                acc[i][j] = __builtin_amdgcn_mfma_f32_16x16x32_bf16(af[i], bfr[j], acc[i][j], 0, 0, 0);
        __syncthreads();
    }

#pragma unroll
    for (int i = 0; i < 4; ++i) {
#pragma unroll
        for (int r = 0; r < 4; ++r) {
            int row = m0 + wm + i * 16 + quad * 4 + r;
            if (row < M) {
#pragma unroll
                for (int j = 0; j < 4; ++j) {
                    int col = n0 + wn + j * 16 + l15;
                    Y[(size_t)row * NW + col] = f2bf(acc[i][j][r]);
                }
            }
        }
    }
}

// ---------------- gathers (CSR, one wave per dst node, no atomics) ----------------
// Y layout: [N][R][F] packed bf16 -> row base (u32 units) = m.x * (F/2), m.x = src*4+r.

// layer 1: F=128 -> 64 u32/row; 4 edges in flight; fused +bias, ReLU, bf16 pack
__global__ __launch_bounds__(256) void gather1(const u32* __restrict__ Y,
                                               const int* __restrict__ off,
                                               const int2* __restrict__ meta,
                                               const float* __restrict__ sb,   // [128]
                                               u32* __restrict__ H1) {         // [NN][64] packed bf16
    int wid  = blockIdx.x * 4 + (threadIdx.x >> 6);
    int lane = threadIdx.x & 63;
    if (wid >= NN) return;
    int j = off[wid], end = off[wid + 1];
    float a0x = 0.f, a0y = 0.f, a1x = 0.f, a1y = 0.f;
    float a2x = 0.f, a2y = 0.f, a3x = 0.f, a3y = 0.f;
    for (; j + 4 <= end; j += 4) {
        int2 m0 = meta[j], m1 = meta[j + 1], m2 = meta[j + 2], m3 = meta[j + 3];
        u32 v0 = Y[(size_t)m0.x * 64 + lane];
        u32 v1 = Y[(size_t)m1.x * 64 + lane];
        u32 v2 = Y[(size_t)m2.x * 64 + lane];
        u32 v3 = Y[(size_t)m3.x * 64 + lane];
        float2 f0 = bfx2(v0), f1 = bfx2(v1), f2 = bfx2(v2), f3 = bfx2(v3);
        float c0 = __int_as_float(m0.y), c1 = __int_as_float(m1.y);
        float c2 = __int_as_float(m2.y), c3 = __int_as_float(m3.y);
        a0x = fmaf(c0, f0.x, a0x); a0y = fmaf(c0, f0.y, a0y);
        a1x = fmaf(c1, f1.x, a1x); a1y = fmaf(c1, f1.y, a1y);
        a2x = fmaf(c2, f2.x, a2x); a2y = fmaf(c2, f2.y, a2y);
        a3x = fmaf(c3, f3.x, a3x); a3y = fmaf(c3, f3.y, a3y);
    }
    for (; j < end; ++j) {
        int2 m0 = meta[j];
        u32 v0 = Y[(size_t)m0.x * 64 + lane];
        float2 f0 = bfx2(v0);
        float c0 = __int_as_float(m0.y);
        a0x = fmaf(c0, f0.x, a0x); a0y = fmaf(c0, f0.y, a0y);
    }
    float2 b = ((const float2*)sb)[lane];
    float ax = fmaxf((a0x + a1x) + (a2x + a3x) + b.x, 0.f);
    float ay = fmaxf((a0y + a1y) + (a2y + a3y) + b.y, 0.f);
    H1[(size_t)wid * 64 + lane] = ((u32)f2bf(ay) << 16) | (u32)f2bf(ax);
}

// layer 2: F=64 -> 32 u32/row; 2 sub-waves x 2 chains = 4 edges in flight; fused +bias
__global__ __launch_bounds__(256) void gather2(const u32* __restrict__ Y,
                                               const int* __restrict__ off,
                                               const int2* __restrict__ meta,
                                               const float* __restrict__ sb,   // [64]
                                               float* __restrict__ out) {      // [NN][64] fp32
    int wid  = blockIdx.x * 4 + (threadIdx.x >> 6);
    int lane = threadIdx.x & 63;
    if (wid >= NN) return;
    int sub = lane >> 5, col = lane & 31;
    int end = off[wid + 1];
    int j = off[wid] + sub;
    float a0x = 0.f, a0y = 0.f, a1x = 0.f, a1y = 0.f;
    for (; j + 2 < end; j += 4) {     // this sub-wave: edges j and j+2
        int2 m0 = meta[j], m1 = meta[j + 2];
        u32 v0 = Y[(size_t)m0.x * 32 + col];
        u32 v1 = Y[(size_t)m1.x * 32 + col];
        float2 f0 = bfx2(v0), f1 = bfx2(v1);
        float c0 = __int_as_float(m0.y), c1 = __int_as_float(m1.y);
        a0x = fmaf(c0, f0.x, a0x); a0y = fmaf(c0, f0.y, a0y);
        a1x = fmaf(c1, f1.x, a1x); a1y = fmaf(c1, f1.y, a1y);
    }
    if (j < end) {
        int2 m0 = meta[j];
        u32 v0 = Y[(size_t)m0.x * 32 + col];
        float2 f0 = bfx2(v0);
        float c0 = __int_as_float(m0.y);
        a0x = fmaf(c0, f0.x, a0x); a0y = fmaf(c0, f0.y, a0y);
    }
    float ax = a0x + a1x, ay = a0y + a1y;
    ax += __shfl_xor(ax, 32);
    ay += __shfl_xor(ay, 32);
    if (sub == 0) {
        float2 b = ((const float2*)sb)[col];
        float2 o = {ax + b.x, ay + b.y};
        ((float2*)out)[(size_t)wid * 32 + col] = o;
    }
}

// ---------------- launch ----------------

extern "C" void kernel_launch(void* const* d_in, const int* in_sizes, int n_in,
                              void* d_out, int out_size, void* d_ws, size_t ws_size,
                              hipStream_t stream) {
    const float* x    = (const float*)d_in[0];
    const int*   esrc = (const int*)  d_in[1];   // [R][E]
    const int*   edst = (const int*)  d_in[2];   // [R][E]
    const float* W1   = (const float*)d_in[3];   // [R][256][128]
    const float* b1   = (const float*)d_in[4];   // [R][128]
    const float* W2   = (const float*)d_in[5];   // [R][128][64]
    const float* b2   = (const float*)d_in[6];   // [R][64]
    float* out = (float*)d_out;                  // [N][64]

    char* w = (char*)d_ws;
    auto alloc = [&](size_t bytes) -> char* {
        char* p = w; w += (bytes + 255) & ~(size_t)255; return p;
    };
    // s_out/s_in adjacent (one rsqrt pass covers both)
    float* s_out  = (float*)alloc((size_t)RR * NN * 4);          // 1.6 MB
    float* s_in   = (float*)alloc((size_t)RR * NN * 4);          // 1.6 MB
    int*   cnt    = (int*)  alloc((size_t)NN * 4);
    int*   off    = (int*)  alloc((size_t)(NN + 1) * 4);
    int*   cursor = (int*)  alloc((size_t)NN * 4);
    int*   bsum   = (int*)  alloc((size_t)NBLK * 4);
    int*   boff   = (int*)  alloc((size_t)NBLK * 4);
    float* sb1    = (float*)alloc(FHID * 4);
    float* sb2    = (float*)alloc(FOUT * 4);
    u16*   W1t    = (u16*)  alloc((size_t)RR * FIN * FHID * 2);
    u16*   W2t    = (u16*)  alloc((size_t)RR * FHID * FOUT * 2);
    int2*  meta   = (int2*) alloc((size_t)RR * EE * 8);          // 16 MB
    u16*   Xbf    = (u16*)  alloc((size_t)NN * FIN * 2);         // 51.2 MB
    u16*   Yall   = (u16*)  alloc((size_t)NN * RR * FHID * 2);   // 102.4 MB, [N][R][F]
    u16*   H1bf   = Xbf;    // Xbf dead after layer-1 GEMM; H1 (25.6 MB) fits
    // total ~175 MB of d_ws

    hipMemsetAsync(s_out, 0, (size_t)2 * RR * NN * 4, stream);   // covers s_in too

    // prep
    conv_bf16x2<<<(NN * FIN / 2 + 255) / 256, 256, 0, stream>>>((const float2*)x, (u32*)Xbf, NN * FIN / 2);
    conv_w_t<<<(RR * FIN * FHID + 255) / 256, 256, 0, stream>>>(W1, W1t, FIN, FHID, RR * FIN * FHID);
    conv_w_t<<<(RR * FHID * FOUT + 255) / 256, 256, 0, stream>>>(W2, W2t, FHID, FOUT, RR * FHID * FOUT);
    deg_kernel<<<(RR * EE + 255) / 256, 256, 0, stream>>>(esrc, edst, s_out, s_in);
    counts_kernel<<<NBLK, 256, 0, stream>>>(s_in, cnt);
    rsqrt_kernel<<<(2 * RR * NN + 255) / 256, 256, 0, stream>>>(s_out, 2 * RR * NN);
    blocksum_kernel<<<NBLK, 256, 0, stream>>>(cnt, bsum);
    scanb_kernel<<<1, 512, 0, stream>>>(bsum, boff);
    offsets_kernel<<<NBLK, 256, 0, stream>>>(cnt, boff, off, cursor);
    fill_kernel<<<(RR * EE + 255) / 256, 256, 0, stream>>>(esrc, edst, s_out, s_in, cursor, meta);
    sumb_kernel<<<1, 192, 0, stream>>>(b1, b2, sb1, sb2);

    // layer 1: one tiled GEMM over all relations (NW = 512), then combined gather
    {
        dim3 grid((NN + 127) / 128, (RR * FHID) / 128);
        gemm_tile<RR * FHID, FIN><<<grid, 256, 0, stream>>>(Xbf, W1t, Yall, NN);
    }
    gather1<<<(NN + 3) / 4, 256, 0, stream>>>((const u32*)Yall, off, meta, sb1, (u32*)H1bf);

    // layer 2: one tiled GEMM over all relations (NW = 256), then combined gather
    {
        dim3 grid((NN + 127) / 128, (RR * FOUT) / 128);
        gemm_tile<RR * FOUT, FHID><<<grid, 256, 0, stream>>>(H1bf, W2t, Yall, NN);
    }
    gather2<<<(NN + 3) / 4, 256, 0, stream>>>((const u32*)Yall, off, meta, sb2, out);
}